// Round 4
// baseline (583.785 us; speedup 1.0000x reference)
//
#include <hip/hip_runtime.h>
#include <hip/hip_fp16.h>

// RelativeMultiHeadAttention on MI355X (gfx950), fp16 MFMA pipeline. Round 4.
//
// R4 changes (R3's reg-staged K/V/Rb spilled to scratch: WRITE_SIZE 8->531 MB):
//  - flash: NO LDS staging for K/V/rel at all. Swapped-score layout makes every
//    MFMA fragment a contiguous 16B global row-slice -> load direct from global
//    (L1 absorbs 4-wave redundancy: K+V+rel tile = 26KB < 32KB L1).
//  - zero __syncthreads in the K-loop; waves fully independent.
//  - LDS = per-wave Qb (skew band + P relayout) only, 11 KB.
//  - T13 defer-max (skip O-rescale when __all(mx - m <= 8)).
//  - qkv/out_proj unchanged from R3 (their reg-prefetch did not regress).
//
// MFMA 16x16x32_f16 fragment convention (m97-verified):
//   A/B operand: row/col = lane&15, k = 8*(lane>>4)+j (8 contiguous halves)
//   C/D:         col = lane&15 (B idx), row = 4*(lane>>4)+reg (A idx)

typedef _Float16 f16;
typedef _Float16 f16x4 __attribute__((ext_vector_type(4)));
typedef _Float16 f16x8 __attribute__((ext_vector_type(8)));
typedef float    f32x4 __attribute__((ext_vector_type(4)));

#define NBATCH 2
#define NHEADS 16
#define DKDIM  64
#define SEQL   2048
#define DMODEL 1024
#define NTOK   4096
#define MAXLEN 2048

// ---------------------------------------------------------------- K0: convert
__global__ void cvt_f32_f16(const float* __restrict__ src, f16* __restrict__ dst, int n4) {
    int i = blockIdx.x * blockDim.x + threadIdx.x;
    if (i < n4) {
        float4 v = ((const float4*)src)[i];
        f16x4 h = { (f16)v.x, (f16)v.y, (f16)v.z, (f16)v.w };
        ((f16x4*)dst)[i] = h;
    }
}

// ------------------------------------------------------------ K1: QKV project
// C[n,o] = sum_i X[n,i]*W[o,i] + b[o]; 128x128 tile, 4 waves (2x2), BK=64,
// register-prefetch double buffer.
__global__ __launch_bounds__(256, 2) void qkv_proj(
    const float* __restrict__ qg, const float* __restrict__ kg, const float* __restrict__ vg,
    const float* __restrict__ wq, const float* __restrict__ wk, const float* __restrict__ wv,
    const float* __restrict__ bq, const float* __restrict__ bk, const float* __restrict__ bv,
    f16* __restrict__ qh, f16* __restrict__ kh, f16* __restrict__ vt)
{
    const int which = blockIdx.z;
    const float* X    = which == 0 ? qg : (which == 1 ? kg : vg);
    const float* W    = which == 0 ? wq : (which == 1 ? wk : wv);
    const float* bias = which == 0 ? bq : (which == 1 ? bk : bv);

    __shared__ f16 As[128][72];
    __shared__ f16 Bs[128][72];

    const int tid = threadIdx.x;
    const int lane = tid & 63;
    const int w = tid >> 6;
    const int wr = w >> 1, wc = w & 1;
    const int row0 = blockIdx.y * 128;
    const int col0 = blockIdx.x * 128;

    f32x4 acc[4][4] = {};
    float4 ra[8], rw[8];

    #pragma unroll
    for (int rep = 0; rep < 8; ++rep) {
        int idx = rep * 256 + tid;
        int r = idx >> 4, seg = idx & 15;
        ra[rep] = *(const float4*)&X[(size_t)(row0 + r) * DMODEL + seg * 4];
        rw[rep] = *(const float4*)&W[(size_t)(col0 + r) * DMODEL + seg * 4];
    }

    for (int kk = 0; kk < DMODEL; kk += 64) {
        #pragma unroll
        for (int rep = 0; rep < 8; ++rep) {
            int idx = rep * 256 + tid;
            int r = idx >> 4, seg = idx & 15;
            f16x4 ha = { (f16)ra[rep].x, (f16)ra[rep].y, (f16)ra[rep].z, (f16)ra[rep].w };
            *(f16x4*)&As[r][seg * 4] = ha;
            f16x4 hb = { (f16)rw[rep].x, (f16)rw[rep].y, (f16)rw[rep].z, (f16)rw[rep].w };
            *(f16x4*)&Bs[r][seg * 4] = hb;
        }
        __syncthreads();
        if (kk + 64 < DMODEL) {
            #pragma unroll
            for (int rep = 0; rep < 8; ++rep) {
                int idx = rep * 256 + tid;
                int r = idx >> 4, seg = idx & 15;
                ra[rep] = *(const float4*)&X[(size_t)(row0 + r) * DMODEL + kk + 64 + seg * 4];
                rw[rep] = *(const float4*)&W[(size_t)(col0 + r) * DMODEL + kk + 64 + seg * 4];
            }
        }
        f16x8 a[4][2], b[4][2];
        #pragma unroll
        for (int mi = 0; mi < 4; ++mi)
            #pragma unroll
            for (int ks = 0; ks < 2; ++ks)
                a[mi][ks] = *(const f16x8*)&As[wr * 64 + mi * 16 + (lane & 15)][ks * 32 + (lane >> 4) * 8];
        #pragma unroll
        for (int ni = 0; ni < 4; ++ni)
            #pragma unroll
            for (int ks = 0; ks < 2; ++ks)
                b[ni][ks] = *(const f16x8*)&Bs[wc * 64 + ni * 16 + (lane & 15)][ks * 32 + (lane >> 4) * 8];
        __builtin_amdgcn_s_setprio(1);
        #pragma unroll
        for (int mi = 0; mi < 4; ++mi)
            #pragma unroll
            for (int ni = 0; ni < 4; ++ni)
                #pragma unroll
                for (int ks = 0; ks < 2; ++ks)
                    acc[mi][ni] = __builtin_amdgcn_mfma_f32_16x16x32_f16(a[mi][ks], b[ni][ks], acc[mi][ni], 0, 0, 0);
        __builtin_amdgcn_s_setprio(0);
        __syncthreads();
    }

    #pragma unroll
    for (int mi = 0; mi < 4; ++mi) {
        #pragma unroll
        for (int ni = 0; ni < 4; ++ni) {
            int col = col0 + wc * 64 + ni * 16 + (lane & 15);
            int h = col >> 6, d = col & 63;
            float bc = bias[col];
            int rowb = row0 + wr * 64 + mi * 16 + (lane >> 4) * 4;
            int b_ = rowb >> 11, l0 = rowb & 2047;
            if (which == 2) {
                f16x4 pk = { (f16)(acc[mi][ni][0] + bc), (f16)(acc[mi][ni][1] + bc),
                             (f16)(acc[mi][ni][2] + bc), (f16)(acc[mi][ni][3] + bc) };
                *(f16x4*)&vt[((size_t)((b_ * 16 + h) * 64 + d)) * 2048 + l0] = pk;
            } else {
                f16* dst = (which == 0) ? qh : kh;
                #pragma unroll
                for (int r = 0; r < 4; ++r)
                    dst[((size_t)((b_ * 16 + h) * 2048 + l0 + r)) * 64 + d] = (f16)(acc[mi][ni][r] + bc);
            }
        }
    }
}

// --------------------------------------------------------- K2: flash attention
// 4 waves; wave w owns Q rows [i0+16w, i0+16w+16). K/V tiles = 64. Swapped-score
// layout (lane = full score row i = lane&15). ALL MFMA operands direct-from-global
// (16B contiguous row slices); LDS = per-wave Qb only; zero barriers in loop.
__global__ __launch_bounds__(256, 3) void flash_attn(
    const f16* __restrict__ qh, const f16* __restrict__ kh, const f16* __restrict__ vt,
    const f16* __restrict__ rel, f16* __restrict__ att)
{
    const int tid = threadIdx.x, lane = tid & 63, w = tid >> 6;
    const int i_l = lane & 15, hi = lane >> 4;
    const int bh = blockIdx.y;
    const int b = bh >> 4, h = bh & 15;
    const int i0 = blockIdx.x * 64;

    __shared__ f16 Qb[4][16][88];       // per-wave: band cols 0..78 / P cols 0..63

    const size_t base_kq = (size_t)bh * SEQL * DKDIM;
    const int pb0 = MAXLEN - i0 - 63;
    const int p0w_off = 48 - w * 16;

    // Q fragment (B-operand) direct from global
    const f16* qrow = &qh[base_kq + (size_t)(i0 + w * 16 + i_l) * 64];
    f16x8 aq[2];
    aq[0] = *(const f16x8*)&qrow[hi * 8];
    aq[1] = *(const f16x8*)&qrow[32 + hi * 8];

    float mrun = -1e30f, lrun = 0.f;
    f32x4 oacc[4] = {};

    for (int j0 = 0; j0 < SEQL; j0 += 64) {
        // ---- S^T = K Q^T : A-frags are 16B slices of kh rows
        f32x4 sacc[4] = {};
        __builtin_amdgcn_s_setprio(1);
        #pragma unroll
        for (int jf = 0; jf < 4; ++jf)
            #pragma unroll
            for (int ks = 0; ks < 2; ++ks) {
                f16x8 ak = *(const f16x8*)&kh[base_kq + (size_t)(j0 + jf * 16 + i_l) * 64 + ks * 32 + hi * 8];
                sacc[jf] = __builtin_amdgcn_mfma_f32_16x16x32_f16(ak, aq[ks], sacc[jf], 0, 0, 0);
            }
        // ---- Qr^T = band Q^T : A-frags are 16B slices of rel rows
        const int p0w = pb0 + j0 + p0w_off;
        f32x4 qracc[5] = {};
        #pragma unroll
        for (int pf = 0; pf < 5; ++pf) {
            int p = p0w + pf * 16 + i_l; if (p > 4095) p = 4095;
            #pragma unroll
            for (int ks = 0; ks < 2; ++ks) {
                f16x8 ar = *(const f16x8*)&rel[(size_t)p * 64 + ks * 32 + hi * 8];
                qracc[pf] = __builtin_amdgcn_mfma_f32_16x16x32_f16(ar, aq[ks], qracc[pf], 0, 0, 0);
            }
        }
        __builtin_amdgcn_s_setprio(0);

        // ---- band -> per-wave LDS, b64-packed
        #pragma unroll
        for (int pf = 0; pf < 5; ++pf) {
            f16x4 pk = { (f16)qracc[pf][0], (f16)qracc[pf][1], (f16)qracc[pf][2], (f16)qracc[pf][3] };
            *(f16x4*)&Qb[w][i_l][pf * 16 + 4 * hi] = pk;
        }

        // ---- skew read + scale
        float p_[4][4];
        #pragma unroll
        for (int nf = 0; nf < 4; ++nf)
            #pragma unroll
            for (int r = 0; r < 4; ++r) {
                int t = nf * 16 + 4 * hi + r - i_l + 15;   // 0..78
                p_[nf][r] = (sacc[nf][r] + (float)Qb[w][i_l][t]) * 0.125f;
            }

        // ---- per-row online softmax with defer-max (row = lane)
        float mx = fmaxf(fmaxf(fmaxf(p_[0][0], p_[0][1]), fmaxf(p_[0][2], p_[0][3])),
                         fmaxf(fmaxf(p_[1][0], p_[1][1]), fmaxf(p_[1][2], p_[1][3])));
        mx = fmaxf(mx, fmaxf(fmaxf(fmaxf(p_[2][0], p_[2][1]), fmaxf(p_[2][2], p_[2][3])),
                             fmaxf(fmaxf(p_[3][0], p_[3][1]), fmaxf(p_[3][2], p_[3][3]))));
        mx = fmaxf(mx, __shfl_xor(mx, 16, 64));
        mx = fmaxf(mx, __shfl_xor(mx, 32, 64));
        if (!__all(mx - mrun <= 8.f)) {
            float mnew = fmaxf(mrun, mx);
            float sc = __expf(mrun - mnew);
            float scb[4];
            #pragma unroll
            for (int r = 0; r < 4; ++r)
                scb[r] = __shfl(sc, (lane & 48) | (4 * hi + r), 64);
            #pragma unroll
            for (int df = 0; df < 4; ++df)
                #pragma unroll
                for (int r = 0; r < 4; ++r) oacc[df][r] *= scb[r];
            lrun *= sc;
            mrun = mnew;
        }
        float sm = 0.f;
        #pragma unroll
        for (int nf = 0; nf < 4; ++nf) {
            #pragma unroll
            for (int r = 0; r < 4; ++r) { p_[nf][r] = __expf(p_[nf][r] - mrun); }
            sm += (p_[nf][0] + p_[nf][1]) + (p_[nf][2] + p_[nf][3]);
        }
        sm += __shfl_xor(sm, 16, 64);
        sm += __shfl_xor(sm, 32, 64);
        lrun += sm;

        // ---- P -> per-wave LDS (b64-packed), read back as A-frags, PV
        #pragma unroll
        for (int nf = 0; nf < 4; ++nf) {
            f16x4 pk = { (f16)p_[nf][0], (f16)p_[nf][1], (f16)p_[nf][2], (f16)p_[nf][3] };
            *(f16x4*)&Qb[w][i_l][nf * 16 + 4 * hi] = pk;
        }
        f16x8 pa[2];
        pa[0] = *(const f16x8*)&Qb[w][i_l][hi * 8];
        pa[1] = *(const f16x8*)&Qb[w][i_l][32 + hi * 8];
        __builtin_amdgcn_s_setprio(1);
        #pragma unroll
        for (int df = 0; df < 4; ++df)
            #pragma unroll
            for (int ks = 0; ks < 2; ++ks) {
                f16x8 bv = *(const f16x8*)&vt[base_kq + (size_t)(df * 16 + i_l) * 2048 + j0 + ks * 32 + hi * 8];
                oacc[df] = __builtin_amdgcn_mfma_f32_16x16x32_f16(pa[ks], bv, oacc[df], 0, 0, 0);
            }
        __builtin_amdgcn_s_setprio(0);
    }

    // ---- epilogue: broadcast lrun to D-layout rows, normalize, write att
    float lb[4];
    #pragma unroll
    for (int r = 0; r < 4; ++r)
        lb[r] = __shfl(lrun, (lane & 48) | (4 * hi + r), 64);
    #pragma unroll
    for (int df = 0; df < 4; ++df) {
        int d = df * 16 + i_l;
        #pragma unroll
        for (int r = 0; r < 4; ++r) {
            int i = i0 + w * 16 + 4 * hi + r;
            float val = oacc[df][r] / lb[r];
            att[((size_t)(b * 2048 + i)) * DMODEL + h * 64 + d] = (f16)val;
        }
    }
}

// ------------------------------------------------------------- K3: out project
__global__ __launch_bounds__(256, 2) void out_proj(
    const f16* __restrict__ att, const float* __restrict__ wo, const float* __restrict__ bo,
    float* __restrict__ out)
{
    __shared__ f16 As[128][72];
    __shared__ f16 Bs[128][72];
    const int tid = threadIdx.x, lane = tid & 63, w = tid >> 6;
    const int wr = w >> 1, wc = w & 1;
    const int row0 = blockIdx.y * 128, col0 = blockIdx.x * 128;

    f32x4 acc[4][4] = {};
    int4 pa_[4];
    float4 pw[8];

    #pragma unroll
    for (int rep = 0; rep < 4; ++rep) {
        int idx = rep * 256 + tid;
        int r = idx >> 3, seg = idx & 7;
        pa_[rep] = *(const int4*)&att[(size_t)(row0 + r) * DMODEL + seg * 8];
    }
    #pragma unroll
    for (int rep = 0; rep < 8; ++rep) {
        int idx = rep * 256 + tid;
        int r = idx >> 4, seg = idx & 15;
        pw[rep] = *(const float4*)&wo[(size_t)(col0 + r) * DMODEL + seg * 4];
    }

    for (int kk = 0; kk < DMODEL; kk += 64) {
        #pragma unroll
        for (int rep = 0; rep < 4; ++rep) {
            int idx = rep * 256 + tid;
            int r = idx >> 3, seg = idx & 7;
            *(int4*)&As[r][seg * 8] = pa_[rep];
        }
        #pragma unroll
        for (int rep = 0; rep < 8; ++rep) {
            int idx = rep * 256 + tid;
            int r = idx >> 4, seg = idx & 15;
            f16x4 hb = { (f16)pw[rep].x, (f16)pw[rep].y, (f16)pw[rep].z, (f16)pw[rep].w };
            *(f16x4*)&Bs[r][seg * 4] = hb;
        }
        __syncthreads();
        if (kk + 64 < DMODEL) {
            #pragma unroll
            for (int rep = 0; rep < 4; ++rep) {
                int idx = rep * 256 + tid;
                int r = idx >> 3, seg = idx & 7;
                pa_[rep] = *(const int4*)&att[(size_t)(row0 + r) * DMODEL + kk + 64 + seg * 8];
            }
            #pragma unroll
            for (int rep = 0; rep < 8; ++rep) {
                int idx = rep * 256 + tid;
                int r = idx >> 4, seg = idx & 15;
                pw[rep] = *(const float4*)&wo[(size_t)(col0 + r) * DMODEL + kk + 64 + seg * 4];
            }
        }
        f16x8 a[4][2], b[4][2];
        #pragma unroll
        for (int mi = 0; mi < 4; ++mi)
            #pragma unroll
            for (int ks = 0; ks < 2; ++ks)
                a[mi][ks] = *(const f16x8*)&As[wr * 64 + mi * 16 + (lane & 15)][ks * 32 + (lane >> 4) * 8];
        #pragma unroll
        for (int ni = 0; ni < 4; ++ni)
            #pragma unroll
            for (int ks = 0; ks < 2; ++ks)
                b[ni][ks] = *(const f16x8*)&Bs[wc * 64 + ni * 16 + (lane & 15)][ks * 32 + (lane >> 4) * 8];
        __builtin_amdgcn_s_setprio(1);
        #pragma unroll
        for (int mi = 0; mi < 4; ++mi)
            #pragma unroll
            for (int ni = 0; ni < 4; ++ni)
                #pragma unroll
                for (int ks = 0; ks < 2; ++ks)
                    acc[mi][ni] = __builtin_amdgcn_mfma_f32_16x16x32_f16(a[mi][ks], b[ni][ks], acc[mi][ni], 0, 0, 0);
        __builtin_amdgcn_s_setprio(0);
        __syncthreads();
    }

    #pragma unroll
    for (int mi = 0; mi < 4; ++mi)
        #pragma unroll
        for (int ni = 0; ni < 4; ++ni) {
            int col = col0 + wc * 64 + ni * 16 + (lane & 15);
            float bc = bo[col];
            #pragma unroll
            for (int r = 0; r < 4; ++r) {
                int row = row0 + wr * 64 + mi * 16 + (lane >> 4) * 4 + r;
                out[(size_t)row * DMODEL + col] = acc[mi][ni][r] + bc;
            }
        }
}

// ----------------------------------------------------------------- launch
extern "C" void kernel_launch(void* const* d_in, const int* in_sizes, int n_in,
                              void* d_out, int out_size, void* d_ws, size_t ws_size,
                              hipStream_t stream) {
    const float* q   = (const float*)d_in[0];
    const float* k   = (const float*)d_in[1];
    const float* v   = (const float*)d_in[2];
    const float* rel = (const float*)d_in[3];
    const float* wq  = (const float*)d_in[4];
    const float* bq  = (const float*)d_in[5];
    const float* wk  = (const float*)d_in[6];
    const float* bk  = (const float*)d_in[7];
    const float* wv  = (const float*)d_in[8];
    const float* bv  = (const float*)d_in[9];
    const float* wo  = (const float*)d_in[10];
    const float* bo  = (const float*)d_in[11];
    float* out = (float*)d_out;

    // workspace layout (halves): rel16 | qh | kh | vt | att
    f16* ws    = (f16*)d_ws;
    f16* rel16 = ws;
    f16* qh16  = rel16 + (size_t)2 * MAXLEN * DKDIM;
    f16* kh16  = qh16 + (size_t)NTOK * DMODEL;
    f16* vt16  = kh16 + (size_t)NTOK * DMODEL;
    f16* att16 = vt16 + (size_t)NTOK * DMODEL;

    cvt_f32_f16<<<dim3(256), 256, 0, stream>>>(rel, rel16, 2 * MAXLEN * DKDIM / 4);
    qkv_proj<<<dim3(8, 32, 3), 256, 0, stream>>>(q, k, v, wq, wk, wv, bq, bk, bv,
                                                 qh16, kh16, vt16);
    flash_attn<<<dim3(32, 32), 256, 0, stream>>>(qh16, kh16, vt16, rel16, att16);
    out_proj<<<dim3(8, 32), 256, 0, stream>>>(att16, wo, bo, out);
}

// Round 5
// 386.292 us; speedup vs baseline: 1.5113x; 1.5113x over previous
//
#include <hip/hip_runtime.h>
#include <hip/hip_fp16.h>

// RelativeMultiHeadAttention on MI355X (gfx950), fp16 MFMA pipeline. Round 5.
//
// R5 changes (R4 was load-latency-bound: MfmaUtil 5.8%, direct-global MFMA
// operands stall ~1200 cyc/tile with nothing to overlap):
//  - flash: K/V/Rb staged in LDS via __builtin_amdgcn_global_load_lds (width 16,
//    no VGPR round-trip, no DS-write instructions, no spill surface).
//  - XOR swizzle (col16 ^= row&7) carried on the per-lane GLOBAL address
//    (linear LDS dest), re-applied on ds_read_b128 -> conflict-free reads.
//  - double-buffered, ONE barrier per tile: issue tile t+1's DMA right after
//    the barrier, compute tile t from the other buffer (full-tile overlap).
//  - swapped-score layout + per-row softmax + defer-max kept from R4 (proven).
//  - qkv_proj / out_proj / cvt unchanged from R4.
//
// MFMA 16x16x32_f16 fragment convention (m97-verified):
//   A/B operand: row/col = lane&15, k = 8*(lane>>4)+j (8 contiguous halves)
//   C/D:         col = lane&15 (B idx), row = 4*(lane>>4)+reg (A idx)

typedef _Float16 f16;
typedef _Float16 f16x4 __attribute__((ext_vector_type(4)));
typedef _Float16 f16x8 __attribute__((ext_vector_type(8)));
typedef float    f32x4 __attribute__((ext_vector_type(4)));

#define NBATCH 2
#define NHEADS 16
#define DKDIM  64
#define SEQL   2048
#define DMODEL 1024
#define NTOK   4096
#define MAXLEN 2048

__device__ __forceinline__ void gload16(const f16* g, f16* l) {
    __builtin_amdgcn_global_load_lds(
        (const __attribute__((address_space(1))) void*)g,
        (__attribute__((address_space(3))) void*)l, 16, 0, 0);
}

// ---------------------------------------------------------------- K0: convert
__global__ void cvt_f32_f16(const float* __restrict__ src, f16* __restrict__ dst, int n4) {
    int i = blockIdx.x * blockDim.x + threadIdx.x;
    if (i < n4) {
        float4 v = ((const float4*)src)[i];
        f16x4 h = { (f16)v.x, (f16)v.y, (f16)v.z, (f16)v.w };
        ((f16x4*)dst)[i] = h;
    }
}

// ------------------------------------------------------------ K1: QKV project
__global__ __launch_bounds__(256, 2) void qkv_proj(
    const float* __restrict__ qg, const float* __restrict__ kg, const float* __restrict__ vg,
    const float* __restrict__ wq, const float* __restrict__ wk, const float* __restrict__ wv,
    const float* __restrict__ bq, const float* __restrict__ bk, const float* __restrict__ bv,
    f16* __restrict__ qh, f16* __restrict__ kh, f16* __restrict__ vt)
{
    const int which = blockIdx.z;
    const float* X    = which == 0 ? qg : (which == 1 ? kg : vg);
    const float* W    = which == 0 ? wq : (which == 1 ? wk : wv);
    const float* bias = which == 0 ? bq : (which == 1 ? bk : bv);

    __shared__ f16 As[128][72];
    __shared__ f16 Bs[128][72];

    const int tid = threadIdx.x;
    const int lane = tid & 63;
    const int w = tid >> 6;
    const int wr = w >> 1, wc = w & 1;
    const int row0 = blockIdx.y * 128;
    const int col0 = blockIdx.x * 128;

    f32x4 acc[4][4] = {};
    float4 ra[8], rw[8];

    #pragma unroll
    for (int rep = 0; rep < 8; ++rep) {
        int idx = rep * 256 + tid;
        int r = idx >> 4, seg = idx & 15;
        ra[rep] = *(const float4*)&X[(size_t)(row0 + r) * DMODEL + seg * 4];
        rw[rep] = *(const float4*)&W[(size_t)(col0 + r) * DMODEL + seg * 4];
    }

    for (int kk = 0; kk < DMODEL; kk += 64) {
        #pragma unroll
        for (int rep = 0; rep < 8; ++rep) {
            int idx = rep * 256 + tid;
            int r = idx >> 4, seg = idx & 15;
            f16x4 ha = { (f16)ra[rep].x, (f16)ra[rep].y, (f16)ra[rep].z, (f16)ra[rep].w };
            *(f16x4*)&As[r][seg * 4] = ha;
            f16x4 hb = { (f16)rw[rep].x, (f16)rw[rep].y, (f16)rw[rep].z, (f16)rw[rep].w };
            *(f16x4*)&Bs[r][seg * 4] = hb;
        }
        __syncthreads();
        if (kk + 64 < DMODEL) {
            #pragma unroll
            for (int rep = 0; rep < 8; ++rep) {
                int idx = rep * 256 + tid;
                int r = idx >> 4, seg = idx & 15;
                ra[rep] = *(const float4*)&X[(size_t)(row0 + r) * DMODEL + kk + 64 + seg * 4];
                rw[rep] = *(const float4*)&W[(size_t)(col0 + r) * DMODEL + kk + 64 + seg * 4];
            }
        }
        f16x8 a[4][2], b[4][2];
        #pragma unroll
        for (int mi = 0; mi < 4; ++mi)
            #pragma unroll
            for (int ks = 0; ks < 2; ++ks)
                a[mi][ks] = *(const f16x8*)&As[wr * 64 + mi * 16 + (lane & 15)][ks * 32 + (lane >> 4) * 8];
        #pragma unroll
        for (int ni = 0; ni < 4; ++ni)
            #pragma unroll
            for (int ks = 0; ks < 2; ++ks)
                b[ni][ks] = *(const f16x8*)&Bs[wc * 64 + ni * 16 + (lane & 15)][ks * 32 + (lane >> 4) * 8];
        __builtin_amdgcn_s_setprio(1);
        #pragma unroll
        for (int mi = 0; mi < 4; ++mi)
            #pragma unroll
            for (int ni = 0; ni < 4; ++ni)
                #pragma unroll
                for (int ks = 0; ks < 2; ++ks)
                    acc[mi][ni] = __builtin_amdgcn_mfma_f32_16x16x32_f16(a[mi][ks], b[ni][ks], acc[mi][ni], 0, 0, 0);
        __builtin_amdgcn_s_setprio(0);
        __syncthreads();
    }

    #pragma unroll
    for (int mi = 0; mi < 4; ++mi) {
        #pragma unroll
        for (int ni = 0; ni < 4; ++ni) {
            int col = col0 + wc * 64 + ni * 16 + (lane & 15);
            int h = col >> 6, d = col & 63;
            float bc = bias[col];
            int rowb = row0 + wr * 64 + mi * 16 + (lane >> 4) * 4;
            int b_ = rowb >> 11, l0 = rowb & 2047;
            if (which == 2) {
                f16x4 pk = { (f16)(acc[mi][ni][0] + bc), (f16)(acc[mi][ni][1] + bc),
                             (f16)(acc[mi][ni][2] + bc), (f16)(acc[mi][ni][3] + bc) };
                *(f16x4*)&vt[((size_t)((b_ * 16 + h) * 64 + d)) * 2048 + l0] = pk;
            } else {
                f16* dst = (which == 0) ? qh : kh;
                #pragma unroll
                for (int r = 0; r < 4; ++r)
                    dst[((size_t)((b_ * 16 + h) * 2048 + l0 + r)) * 64 + d] = (f16)(acc[mi][ni][r] + bc);
            }
        }
    }
}

// --------------------------------------------------------- K2: flash attention
// 4 waves; wave w owns Q rows [i0+16w, i0+16w+16). Swapped-score layout.
// K/V/Rb double-buffered in LDS via global_load_lds (pre-swizzled source),
// one barrier per tile; DMA for tile t+1 overlaps compute of tile t.
__global__ __launch_bounds__(256, 2) void flash_attn(
    const f16* __restrict__ qh, const f16* __restrict__ kh, const f16* __restrict__ vt,
    const f16* __restrict__ rel, f16* __restrict__ att)
{
    const int tid = threadIdx.x, lane = tid & 63, w = tid >> 6;
    const int i_l = lane & 15, hi = lane >> 4;
    const int bh = blockIdx.y;
    const int b = bh >> 4, h = bh & 15;
    const int i0 = blockIdx.x * 64;

    // per buffer (16384 halves): Ks [0,4096) rows 64x64 | Vs [4096,8192) | Rb [8192,16384) rows 128x64
    __shared__ f16 Stage[2][16384];
    __shared__ f16 Qb[4][16][88];       // per-wave: band cols 0..78 / P cols 0..63

    const size_t base_kq = (size_t)bh * SEQL * DKDIM;
    const int pb0 = MAXLEN - i0 - 63;   // abs rel row of band window start at j0=0 (>=1)
    const int t0 = 48 - w * 16;         // per-wave band row offset in staged window

    // staging lane decomposition: lane = 8*lr + lc, writes LDS at +lane*16B
    const int lr = lane >> 3;           // row within 8-row chunk
    const int lc = lane & 7;            // 16B unit within 128B row
    const int sc = (lc ^ lr) << 3;      // swizzled source col (halves)

    // ---- Q fragment (B-operand) direct from global
    const f16* qrow = &qh[base_kq + (size_t)(i0 + w * 16 + i_l) * 64];
    f16x8 aq[2];
    aq[0] = *(const f16x8*)&qrow[hi * 8];
    aq[1] = *(const f16x8*)&qrow[32 + hi * 8];

    // ---- issue tile 0 into buffer 0
    {
        f16* sb = &Stage[0][0];
        #pragma unroll
        for (int c = 0; c < 2; ++c) {
            int row = w * 16 + c * 8;
            gload16(&kh[base_kq + (size_t)(row + lr) * 64 + sc], &sb[row * 64]);
            gload16(&vt[base_kq + (size_t)(row + lr) * 2048 + 0 + sc], &sb[4096 + row * 64]);
        }
        #pragma unroll
        for (int c = 0; c < 4; ++c) {
            int rrow = w * 32 + c * 8;
            int p = pb0 + rrow + lr; if (p > 4095) p = 4095;
            gload16(&rel[(size_t)p * 64 + sc], &sb[8192 + rrow * 64]);
        }
    }

    float mrun = -1e30f, lrun = 0.f;    // per-lane = per score row i
    f32x4 oacc[4] = {};
    int cur = 0;

    const int sw0 = (hi ^ (i_l & 7)) << 3;   // swizzled read offset, ks=0 (halves)
    const int sw1 = sw0 ^ 32;                // ks=1

    for (int j0 = 0; j0 < SEQL; j0 += 64) {
        __syncthreads();                // drains DMA -> Stage[cur] ready; all waves past buf[cur^1]

        // ---- issue next tile into the other buffer (overlaps this tile's compute)
        if (j0 + 64 < SEQL) {
            f16* sb = &Stage[cur ^ 1][0];
            const int jn = j0 + 64;
            #pragma unroll
            for (int c = 0; c < 2; ++c) {
                int row = w * 16 + c * 8;
                gload16(&kh[base_kq + (size_t)(jn + row + lr) * 64 + sc], &sb[row * 64]);
                gload16(&vt[base_kq + (size_t)(row + lr) * 2048 + jn + sc], &sb[4096 + row * 64]);
            }
            #pragma unroll
            for (int c = 0; c < 4; ++c) {
                int rrow = w * 32 + c * 8;
                int p = pb0 + jn + rrow + lr; if (p > 4095) p = 4095;
                gload16(&rel[(size_t)p * 64 + sc], &sb[8192 + rrow * 64]);
            }
        }

        const f16* sb = &Stage[cur][0];

        // ---- S^T = K Q^T
        f32x4 sacc[4] = {};
        __builtin_amdgcn_s_setprio(1);
        #pragma unroll
        for (int jf = 0; jf < 4; ++jf) {
            f16x8 ak0 = *(const f16x8*)&sb[(jf * 16 + i_l) * 64 + sw0];
            f16x8 ak1 = *(const f16x8*)&sb[(jf * 16 + i_l) * 64 + sw1];
            sacc[jf] = __builtin_amdgcn_mfma_f32_16x16x32_f16(ak0, aq[0], sacc[jf], 0, 0, 0);
            sacc[jf] = __builtin_amdgcn_mfma_f32_16x16x32_f16(ak1, aq[1], sacc[jf], 0, 0, 0);
        }
        // ---- Qr^T = band Q^T (per-wave 80-col band from staged window)
        f32x4 qracc[5] = {};
        #pragma unroll
        for (int pf = 0; pf < 5; ++pf) {
            int rrow = 8192 + (t0 + pf * 16 + i_l) * 64;
            f16x8 ar0 = *(const f16x8*)&sb[rrow + sw0];
            f16x8 ar1 = *(const f16x8*)&sb[rrow + sw1];
            qracc[pf] = __builtin_amdgcn_mfma_f32_16x16x32_f16(ar0, aq[0], qracc[pf], 0, 0, 0);
            qracc[pf] = __builtin_amdgcn_mfma_f32_16x16x32_f16(ar1, aq[1], qracc[pf], 0, 0, 0);
        }
        __builtin_amdgcn_s_setprio(0);

        // ---- band -> per-wave LDS, b64-packed
        #pragma unroll
        for (int pf = 0; pf < 5; ++pf) {
            f16x4 pk = { (f16)qracc[pf][0], (f16)qracc[pf][1], (f16)qracc[pf][2], (f16)qracc[pf][3] };
            *(f16x4*)&Qb[w][i_l][pf * 16 + 4 * hi] = pk;
        }

        // ---- skew read + scale: (i = i_l, j = nf*16 + 4*hi + r)
        float p_[4][4];
        #pragma unroll
        for (int nf = 0; nf < 4; ++nf)
            #pragma unroll
            for (int r = 0; r < 4; ++r) {
                int t = nf * 16 + 4 * hi + r - i_l + 15;   // 0..78
                p_[nf][r] = (sacc[nf][r] + (float)Qb[w][i_l][t]) * 0.125f;
            }

        // ---- per-row online softmax with defer-max (row = lane)
        float mx = fmaxf(fmaxf(fmaxf(p_[0][0], p_[0][1]), fmaxf(p_[0][2], p_[0][3])),
                         fmaxf(fmaxf(p_[1][0], p_[1][1]), fmaxf(p_[1][2], p_[1][3])));
        mx = fmaxf(mx, fmaxf(fmaxf(fmaxf(p_[2][0], p_[2][1]), fmaxf(p_[2][2], p_[2][3])),
                             fmaxf(fmaxf(p_[3][0], p_[3][1]), fmaxf(p_[3][2], p_[3][3]))));
        mx = fmaxf(mx, __shfl_xor(mx, 16, 64));
        mx = fmaxf(mx, __shfl_xor(mx, 32, 64));
        if (!__all(mx - mrun <= 8.f)) {
            float mnew = fmaxf(mrun, mx);
            float scv = __expf(mrun - mnew);
            float scb[4];
            #pragma unroll
            for (int r = 0; r < 4; ++r)
                scb[r] = __shfl(scv, (lane & 48) | (4 * hi + r), 64);
            #pragma unroll
            for (int df = 0; df < 4; ++df)
                #pragma unroll
                for (int r = 0; r < 4; ++r) oacc[df][r] *= scb[r];
            lrun *= scv;
            mrun = mnew;
        }
        float sm = 0.f;
        #pragma unroll
        for (int nf = 0; nf < 4; ++nf) {
            #pragma unroll
            for (int r = 0; r < 4; ++r) { p_[nf][r] = __expf(p_[nf][r] - mrun); }
            sm += (p_[nf][0] + p_[nf][1]) + (p_[nf][2] + p_[nf][3]);
        }
        sm += __shfl_xor(sm, 16, 64);
        sm += __shfl_xor(sm, 32, 64);
        lrun += sm;

        // ---- P -> per-wave LDS (b64-packed), read back as A-frags, PV
        #pragma unroll
        for (int nf = 0; nf < 4; ++nf) {
            f16x4 pk = { (f16)p_[nf][0], (f16)p_[nf][1], (f16)p_[nf][2], (f16)p_[nf][3] };
            *(f16x4*)&Qb[w][i_l][nf * 16 + 4 * hi] = pk;
        }
        f16x8 pa[2];
        pa[0] = *(const f16x8*)&Qb[w][i_l][hi * 8];
        pa[1] = *(const f16x8*)&Qb[w][i_l][32 + hi * 8];
        __builtin_amdgcn_s_setprio(1);
        #pragma unroll
        for (int df = 0; df < 4; ++df) {
            f16x8 bv0 = *(const f16x8*)&sb[4096 + (df * 16 + i_l) * 64 + sw0];
            f16x8 bv1 = *(const f16x8*)&sb[4096 + (df * 16 + i_l) * 64 + sw1];
            oacc[df] = __builtin_amdgcn_mfma_f32_16x16x32_f16(pa[0], bv0, oacc[df], 0, 0, 0);
            oacc[df] = __builtin_amdgcn_mfma_f32_16x16x32_f16(pa[1], bv1, oacc[df], 0, 0, 0);
        }
        __builtin_amdgcn_s_setprio(0);
        cur ^= 1;
    }

    // ---- epilogue: broadcast lrun to D-layout rows, normalize, write att
    float lb[4];
    #pragma unroll
    for (int r = 0; r < 4; ++r)
        lb[r] = __shfl(lrun, (lane & 48) | (4 * hi + r), 64);
    #pragma unroll
    for (int df = 0; df < 4; ++df) {
        int d = df * 16 + i_l;
        #pragma unroll
        for (int r = 0; r < 4; ++r) {
            int i = i0 + w * 16 + 4 * hi + r;
            float val = oacc[df][r] / lb[r];
            att[((size_t)(b * 2048 + i)) * DMODEL + h * 64 + d] = (f16)val;
        }
    }
}

// ------------------------------------------------------------- K3: out project
__global__ __launch_bounds__(256, 2) void out_proj(
    const f16* __restrict__ att, const float* __restrict__ wo, const float* __restrict__ bo,
    float* __restrict__ out)
{
    __shared__ f16 As[128][72];
    __shared__ f16 Bs[128][72];
    const int tid = threadIdx.x, lane = tid & 63, w = tid >> 6;
    const int wr = w >> 1, wc = w & 1;
    const int row0 = blockIdx.y * 128, col0 = blockIdx.x * 128;

    f32x4 acc[4][4] = {};
    int4 pa_[4];
    float4 pw[8];

    #pragma unroll
    for (int rep = 0; rep < 4; ++rep) {
        int idx = rep * 256 + tid;
        int r = idx >> 3, seg = idx & 7;
        pa_[rep] = *(const int4*)&att[(size_t)(row0 + r) * DMODEL + seg * 8];
    }
    #pragma unroll
    for (int rep = 0; rep < 8; ++rep) {
        int idx = rep * 256 + tid;
        int r = idx >> 4, seg = idx & 15;
        pw[rep] = *(const float4*)&wo[(size_t)(col0 + r) * DMODEL + seg * 4];
    }

    for (int kk = 0; kk < DMODEL; kk += 64) {
        #pragma unroll
        for (int rep = 0; rep < 4; ++rep) {
            int idx = rep * 256 + tid;
            int r = idx >> 3, seg = idx & 7;
            *(int4*)&As[r][seg * 8] = pa_[rep];
        }
        #pragma unroll
        for (int rep = 0; rep < 8; ++rep) {
            int idx = rep * 256 + tid;
            int r = idx >> 4, seg = idx & 15;
            f16x4 hb = { (f16)pw[rep].x, (f16)pw[rep].y, (f16)pw[rep].z, (f16)pw[rep].w };
            *(f16x4*)&Bs[r][seg * 4] = hb;
        }
        __syncthreads();
        if (kk + 64 < DMODEL) {
            #pragma unroll
            for (int rep = 0; rep < 4; ++rep) {
                int idx = rep * 256 + tid;
                int r = idx >> 3, seg = idx & 7;
                pa_[rep] = *(const int4*)&att[(size_t)(row0 + r) * DMODEL + kk + 64 + seg * 8];
            }
            #pragma unroll
            for (int rep = 0; rep < 8; ++rep) {
                int idx = rep * 256 + tid;
                int r = idx >> 4, seg = idx & 15;
                pw[rep] = *(const float4*)&wo[(size_t)(col0 + r) * DMODEL + kk + 64 + seg * 4];
            }
        }
        f16x8 a[4][2], b[4][2];
        #pragma unroll
        for (int mi = 0; mi < 4; ++mi)
            #pragma unroll
            for (int ks = 0; ks < 2; ++ks)
                a[mi][ks] = *(const f16x8*)&As[wr * 64 + mi * 16 + (lane & 15)][ks * 32 + (lane >> 4) * 8];
        #pragma unroll
        for (int ni = 0; ni < 4; ++ni)
            #pragma unroll
            for (int ks = 0; ks < 2; ++ks)
                b[ni][ks] = *(const f16x8*)&Bs[wc * 64 + ni * 16 + (lane & 15)][ks * 32 + (lane >> 4) * 8];
        __builtin_amdgcn_s_setprio(1);
        #pragma unroll
        for (int mi = 0; mi < 4; ++mi)
            #pragma unroll
            for (int ni = 0; ni < 4; ++ni)
                #pragma unroll
                for (int ks = 0; ks < 2; ++ks)
                    acc[mi][ni] = __builtin_amdgcn_mfma_f32_16x16x32_f16(a[mi][ks], b[ni][ks], acc[mi][ni], 0, 0, 0);
        __builtin_amdgcn_s_setprio(0);
        __syncthreads();
    }

    #pragma unroll
    for (int mi = 0; mi < 4; ++mi)
        #pragma unroll
        for (int ni = 0; ni < 4; ++ni) {
            int col = col0 + wc * 64 + ni * 16 + (lane & 15);
            float bc = bo[col];
            #pragma unroll
            for (int r = 0; r < 4; ++r) {
                int row = row0 + wr * 64 + mi * 16 + (lane >> 4) * 4 + r;
                out[(size_t)row * DMODEL + col] = acc[mi][ni][r] + bc;
            }
        }
}

// ----------------------------------------------------------------- launch
extern "C" void kernel_launch(void* const* d_in, const int* in_sizes, int n_in,
                              void* d_out, int out_size, void* d_ws, size_t ws_size,
                              hipStream_t stream) {
    const float* q   = (const float*)d_in[0];
    const float* k   = (const float*)d_in[1];
    const float* v   = (const float*)d_in[2];
    const float* rel = (const float*)d_in[3];
    const float* wq  = (const float*)d_in[4];
    const float* bq  = (const float*)d_in[5];
    const float* wk  = (const float*)d_in[6];
    const float* bk  = (const float*)d_in[7];
    const float* wv  = (const float*)d_in[8];
    const float* bv  = (const float*)d_in[9];
    const float* wo  = (const float*)d_in[10];
    const float* bo  = (const float*)d_in[11];
    float* out = (float*)d_out;

    // workspace layout (halves): rel16 | qh | kh | vt | att
    f16* ws    = (f16*)d_ws;
    f16* rel16 = ws;
    f16* qh16  = rel16 + (size_t)2 * MAXLEN * DKDIM;
    f16* kh16  = qh16 + (size_t)NTOK * DMODEL;
    f16* vt16  = kh16 + (size_t)NTOK * DMODEL;
    f16* att16 = vt16 + (size_t)NTOK * DMODEL;

    cvt_f32_f16<<<dim3(256), 256, 0, stream>>>(rel, rel16, 2 * MAXLEN * DKDIM / 4);
    qkv_proj<<<dim3(8, 32, 3), 256, 0, stream>>>(q, k, v, wq, wk, wv, bq, bk, bv,
                                                 qh16, kh16, vt16);
    flash_attn<<<dim3(32, 32), 256, 0, stream>>>(qh16, kh16, vt16, rel16, att16);
    out_proj<<<dim3(8, 32), 256, 0, stream>>>(att16, wo, bo, out);
}

// Round 6
// 356.357 us; speedup vs baseline: 1.6382x; 1.0840x over previous
//
#include <hip/hip_runtime.h>
#include <hip/hip_fp16.h>

// RelativeMultiHeadAttention on MI355X (gfx950), fp16 MFMA pipeline. Round 6.
//
// R6 changes (non-flash was ~198us > flash 188us; projections were fp32-load,
// VALU-convert, low-occupancy, L2-unfriendly):
//  - cvt_all: single grid-stride kernel converts q,k,v,wq,wk,wv,wo,rel -> fp16
//  - qkv_proj/out_proj: m97-style fp16 GEMM, global_load_lds (width 16) with
//    source-side XOR swizzle (validated in flash R5), BK=64, 2 barriers/step,
//    no reg prefetch (VGPR ~130 -> 3 blocks/CU), XCD-bijective tile swizzle
//    (32 logical tiles/XCD: 4 X-panels + 8 W-panels = 3MB fits 4MB XCD L2)
//  - flash_attn: UNCHANGED from R5 (188us, validated)
//  - ws: att16 aliases dead x16q region; total 59.2MB
//
// MFMA 16x16x32_f16 fragment convention (m97-verified):
//   A/B operand: row/col = lane&15, k = 8*(lane>>4)+j (8 contiguous halves)
//   C/D:         col = lane&15 (B idx), row = 4*(lane>>4)+reg (A idx)

typedef _Float16 f16;
typedef _Float16 f16x4 __attribute__((ext_vector_type(4)));
typedef _Float16 f16x8 __attribute__((ext_vector_type(8)));
typedef float    f32x4 __attribute__((ext_vector_type(4)));

#define NBATCH 2
#define NHEADS 16
#define DKDIM  64
#define SEQL   2048
#define DMODEL 1024
#define NTOK   4096
#define MAXLEN 2048

__device__ __forceinline__ void gload16(const f16* g, f16* l) {
    __builtin_amdgcn_global_load_lds(
        (const __attribute__((address_space(1))) void*)g,
        (__attribute__((address_space(3))) void*)l, 16, 0, 0);
}

// ------------------------------------------------------- K0: convert everything
// dst layout (f16, float4-chunk order): q | k | v | wq | wk | wv | wo | rel
__global__ void cvt_all(
    const float* __restrict__ q, const float* __restrict__ k, const float* __restrict__ v,
    const float* __restrict__ wq, const float* __restrict__ wk, const float* __restrict__ wv,
    const float* __restrict__ wo, const float* __restrict__ rel, f16* __restrict__ dst)
{
    const int SX = 1048576;   // 4096*1024/4
    const int SW = 262144;    // 1024*1024/4
    const int SR = 65536;     // 2*2048*64/4
    const int total = 3 * SX + 4 * SW + SR;
    for (int i = blockIdx.x * blockDim.x + threadIdx.x; i < total; i += gridDim.x * blockDim.x) {
        int j = i;
        const float* s;
        if (j < SX) s = q;
        else if ((j -= SX) < SX) s = k;
        else if ((j -= SX) < SX) s = v;
        else if ((j -= SX) < SW) s = wq;
        else if ((j -= SW) < SW) s = wk;
        else if ((j -= SW) < SW) s = wv;
        else if ((j -= SW) < SW) s = wo;
        else { j -= SW; s = rel; }
        float4 vv = ((const float4*)s)[j];
        f16x4 h = { (f16)vv.x, (f16)vv.y, (f16)vv.z, (f16)vv.w };
        ((f16x4*)dst)[i] = h;
    }
}

// ------------------------------------------------------------ K1: QKV project
// C[n,o] = sum_i X[n,i]*W[o,i] + b[o]; fp16 in, 128x128 tile, 4 waves (2x2),
// BK=64, global_load_lds staging with XOR-swizzled source, XCD tile swizzle.
__global__ __launch_bounds__(256, 3) void qkv_proj(
    const f16* __restrict__ xq, const f16* __restrict__ xk, const f16* __restrict__ xv,
    const f16* __restrict__ wq16, const f16* __restrict__ wk16, const f16* __restrict__ wv16,
    const float* __restrict__ bq, const float* __restrict__ bk, const float* __restrict__ bv,
    f16* __restrict__ qh, f16* __restrict__ kh, f16* __restrict__ vt)
{
    const int which = blockIdx.z;
    const f16* X      = which == 0 ? xq : (which == 1 ? xk : xv);
    const f16* W      = which == 0 ? wq16 : (which == 1 ? wk16 : wv16);
    const float* bias = which == 0 ? bq : (which == 1 ? bk : bv);

    __shared__ f16 As[128 * 64];
    __shared__ f16 Bs[128 * 64];

    const int tid = threadIdx.x, lane = tid & 63, w = tid >> 6;
    const int i_l = lane & 15, hi = lane >> 4;
    const int wr = w >> 1, wc = w & 1;

    // XCD-bijective tile swizzle: 256 tiles, 32 consecutive logical per XCD
    const int nbid = blockIdx.y * 8 + blockIdx.x;
    const int swz = (nbid & 7) * 32 + (nbid >> 3);
    const int row0 = (swz >> 3) * 128;
    const int col0 = (swz & 7) * 128;

    // staging decomposition: lane = 8*lr + lc; LDS linear, source col swizzled
    const int lr = lane >> 3, lc = lane & 7;
    const int sc = (lc ^ lr) << 3;

    f32x4 acc[4][4] = {};

    for (int kk = 0; kk < DMODEL; kk += 64) {
        #pragma unroll
        for (int c = 0; c < 4; ++c) {
            int row = w * 32 + c * 8;
            gload16(&X[(size_t)(row0 + row + lr) * DMODEL + kk + sc], &As[row * 64]);
            gload16(&W[(size_t)(col0 + row + lr) * DMODEL + kk + sc], &Bs[row * 64]);
        }
        __syncthreads();   // drains DMA

        f16x8 bfr[4][2];
        #pragma unroll
        for (int ni = 0; ni < 4; ++ni)
            #pragma unroll
            for (int ks = 0; ks < 2; ++ks)
                bfr[ni][ks] = *(const f16x8*)&Bs[(wc * 64 + ni * 16 + i_l) * 64 + (((ks * 4 + hi) ^ (i_l & 7)) << 3)];
        __builtin_amdgcn_s_setprio(1);
        #pragma unroll
        for (int mi = 0; mi < 4; ++mi) {
            f16x8 afr[2];
            #pragma unroll
            for (int ks = 0; ks < 2; ++ks)
                afr[ks] = *(const f16x8*)&As[(wr * 64 + mi * 16 + i_l) * 64 + (((ks * 4 + hi) ^ (i_l & 7)) << 3)];
            #pragma unroll
            for (int ni = 0; ni < 4; ++ni)
                #pragma unroll
                for (int ks = 0; ks < 2; ++ks)
                    acc[mi][ni] = __builtin_amdgcn_mfma_f32_16x16x32_f16(afr[ks], bfr[ni][ks], acc[mi][ni], 0, 0, 0);
        }
        __builtin_amdgcn_s_setprio(0);
        __syncthreads();   // WAR before next stage
    }

    // epilogue: +bias, scatter into head layouts
    #pragma unroll
    for (int mi = 0; mi < 4; ++mi) {
        #pragma unroll
        for (int ni = 0; ni < 4; ++ni) {
            int col = col0 + wc * 64 + ni * 16 + i_l;
            int h = col >> 6, d = col & 63;
            float bc = bias[col];
            int rowb = row0 + wr * 64 + mi * 16 + hi * 4;
            int b_ = rowb >> 11, l0 = rowb & 2047;
            if (which == 2) {
                f16x4 pk = { (f16)(acc[mi][ni][0] + bc), (f16)(acc[mi][ni][1] + bc),
                             (f16)(acc[mi][ni][2] + bc), (f16)(acc[mi][ni][3] + bc) };
                *(f16x4*)&vt[((size_t)((b_ * 16 + h) * 64 + d)) * 2048 + l0] = pk;
            } else {
                f16* dst = (which == 0) ? qh : kh;
                #pragma unroll
                for (int r = 0; r < 4; ++r)
                    dst[((size_t)((b_ * 16 + h) * 2048 + l0 + r)) * 64 + d] = (f16)(acc[mi][ni][r] + bc);
            }
        }
    }
}

// --------------------------------------------------------- K2: flash attention
// UNCHANGED from R5 (validated, 188us).
__global__ __launch_bounds__(256, 2) void flash_attn(
    const f16* __restrict__ qh, const f16* __restrict__ kh, const f16* __restrict__ vt,
    const f16* __restrict__ rel, f16* __restrict__ att)
{
    const int tid = threadIdx.x, lane = tid & 63, w = tid >> 6;
    const int i_l = lane & 15, hi = lane >> 4;
    const int bh = blockIdx.y;
    const int b = bh >> 4, h = bh & 15;
    const int i0 = blockIdx.x * 64;

    __shared__ f16 Stage[2][16384];
    __shared__ f16 Qb[4][16][88];

    const size_t base_kq = (size_t)bh * SEQL * DKDIM;
    const int pb0 = MAXLEN - i0 - 63;
    const int t0 = 48 - w * 16;

    const int lr = lane >> 3;
    const int lc = lane & 7;
    const int sc = (lc ^ lr) << 3;

    const f16* qrow = &qh[base_kq + (size_t)(i0 + w * 16 + i_l) * 64];
    f16x8 aq[2];
    aq[0] = *(const f16x8*)&qrow[hi * 8];
    aq[1] = *(const f16x8*)&qrow[32 + hi * 8];

    {
        f16* sb = &Stage[0][0];
        #pragma unroll
        for (int c = 0; c < 2; ++c) {
            int row = w * 16 + c * 8;
            gload16(&kh[base_kq + (size_t)(row + lr) * 64 + sc], &sb[row * 64]);
            gload16(&vt[base_kq + (size_t)(row + lr) * 2048 + 0 + sc], &sb[4096 + row * 64]);
        }
        #pragma unroll
        for (int c = 0; c < 4; ++c) {
            int rrow = w * 32 + c * 8;
            int p = pb0 + rrow + lr; if (p > 4095) p = 4095;
            gload16(&rel[(size_t)p * 64 + sc], &sb[8192 + rrow * 64]);
        }
    }

    float mrun = -1e30f, lrun = 0.f;
    f32x4 oacc[4] = {};
    int cur = 0;

    const int sw0 = (hi ^ (i_l & 7)) << 3;
    const int sw1 = sw0 ^ 32;

    for (int j0 = 0; j0 < SEQL; j0 += 64) {
        __syncthreads();

        if (j0 + 64 < SEQL) {
            f16* sb = &Stage[cur ^ 1][0];
            const int jn = j0 + 64;
            #pragma unroll
            for (int c = 0; c < 2; ++c) {
                int row = w * 16 + c * 8;
                gload16(&kh[base_kq + (size_t)(jn + row + lr) * 64 + sc], &sb[row * 64]);
                gload16(&vt[base_kq + (size_t)(row + lr) * 2048 + jn + sc], &sb[4096 + row * 64]);
            }
            #pragma unroll
            for (int c = 0; c < 4; ++c) {
                int rrow = w * 32 + c * 8;
                int p = pb0 + jn + rrow + lr; if (p > 4095) p = 4095;
                gload16(&rel[(size_t)p * 64 + sc], &sb[8192 + rrow * 64]);
            }
        }

        const f16* sb = &Stage[cur][0];

        f32x4 sacc[4] = {};
        __builtin_amdgcn_s_setprio(1);
        #pragma unroll
        for (int jf = 0; jf < 4; ++jf) {
            f16x8 ak0 = *(const f16x8*)&sb[(jf * 16 + i_l) * 64 + sw0];
            f16x8 ak1 = *(const f16x8*)&sb[(jf * 16 + i_l) * 64 + sw1];
            sacc[jf] = __builtin_amdgcn_mfma_f32_16x16x32_f16(ak0, aq[0], sacc[jf], 0, 0, 0);
            sacc[jf] = __builtin_amdgcn_mfma_f32_16x16x32_f16(ak1, aq[1], sacc[jf], 0, 0, 0);
        }
        f32x4 qracc[5] = {};
        #pragma unroll
        for (int pf = 0; pf < 5; ++pf) {
            int rrow = 8192 + (t0 + pf * 16 + i_l) * 64;
            f16x8 ar0 = *(const f16x8*)&sb[rrow + sw0];
            f16x8 ar1 = *(const f16x8*)&sb[rrow + sw1];
            qracc[pf] = __builtin_amdgcn_mfma_f32_16x16x32_f16(ar0, aq[0], qracc[pf], 0, 0, 0);
            qracc[pf] = __builtin_amdgcn_mfma_f32_16x16x32_f16(ar1, aq[1], qracc[pf], 0, 0, 0);
        }
        __builtin_amdgcn_s_setprio(0);

        #pragma unroll
        for (int pf = 0; pf < 5; ++pf) {
            f16x4 pk = { (f16)qracc[pf][0], (f16)qracc[pf][1], (f16)qracc[pf][2], (f16)qracc[pf][3] };
            *(f16x4*)&Qb[w][i_l][pf * 16 + 4 * hi] = pk;
        }

        float p_[4][4];
        #pragma unroll
        for (int nf = 0; nf < 4; ++nf)
            #pragma unroll
            for (int r = 0; r < 4; ++r) {
                int t = nf * 16 + 4 * hi + r - i_l + 15;
                p_[nf][r] = (sacc[nf][r] + (float)Qb[w][i_l][t]) * 0.125f;
            }

        float mx = fmaxf(fmaxf(fmaxf(p_[0][0], p_[0][1]), fmaxf(p_[0][2], p_[0][3])),
                         fmaxf(fmaxf(p_[1][0], p_[1][1]), fmaxf(p_[1][2], p_[1][3])));
        mx = fmaxf(mx, fmaxf(fmaxf(fmaxf(p_[2][0], p_[2][1]), fmaxf(p_[2][2], p_[2][3])),
                             fmaxf(fmaxf(p_[3][0], p_[3][1]), fmaxf(p_[3][2], p_[3][3]))));
        mx = fmaxf(mx, __shfl_xor(mx, 16, 64));
        mx = fmaxf(mx, __shfl_xor(mx, 32, 64));
        if (!__all(mx - mrun <= 8.f)) {
            float mnew = fmaxf(mrun, mx);
            float scv = __expf(mrun - mnew);
            float scb[4];
            #pragma unroll
            for (int r = 0; r < 4; ++r)
                scb[r] = __shfl(scv, (lane & 48) | (4 * hi + r), 64);
            #pragma unroll
            for (int df = 0; df < 4; ++df)
                #pragma unroll
                for (int r = 0; r < 4; ++r) oacc[df][r] *= scb[r];
            lrun *= scv;
            mrun = mnew;
        }
        float sm = 0.f;
        #pragma unroll
        for (int nf = 0; nf < 4; ++nf) {
            #pragma unroll
            for (int r = 0; r < 4; ++r) { p_[nf][r] = __expf(p_[nf][r] - mrun); }
            sm += (p_[nf][0] + p_[nf][1]) + (p_[nf][2] + p_[nf][3]);
        }
        sm += __shfl_xor(sm, 16, 64);
        sm += __shfl_xor(sm, 32, 64);
        lrun += sm;

        #pragma unroll
        for (int nf = 0; nf < 4; ++nf) {
            f16x4 pk = { (f16)p_[nf][0], (f16)p_[nf][1], (f16)p_[nf][2], (f16)p_[nf][3] };
            *(f16x4*)&Qb[w][i_l][nf * 16 + 4 * hi] = pk;
        }
        f16x8 pa[2];
        pa[0] = *(const f16x8*)&Qb[w][i_l][hi * 8];
        pa[1] = *(const f16x8*)&Qb[w][i_l][32 + hi * 8];
        __builtin_amdgcn_s_setprio(1);
        #pragma unroll
        for (int df = 0; df < 4; ++df) {
            f16x8 bv0 = *(const f16x8*)&sb[4096 + (df * 16 + i_l) * 64 + sw0];
            f16x8 bv1 = *(const f16x8*)&sb[4096 + (df * 16 + i_l) * 64 + sw1];
            oacc[df] = __builtin_amdgcn_mfma_f32_16x16x32_f16(pa[0], bv0, oacc[df], 0, 0, 0);
            oacc[df] = __builtin_amdgcn_mfma_f32_16x16x32_f16(pa[1], bv1, oacc[df], 0, 0, 0);
        }
        __builtin_amdgcn_s_setprio(0);
        cur ^= 1;
    }

    float lb[4];
    #pragma unroll
    for (int r = 0; r < 4; ++r)
        lb[r] = __shfl(lrun, (lane & 48) | (4 * hi + r), 64);
    #pragma unroll
    for (int df = 0; df < 4; ++df) {
        int d = df * 16 + i_l;
        #pragma unroll
        for (int r = 0; r < 4; ++r) {
            int i = i0 + w * 16 + 4 * hi + r;
            float val = oacc[df][r] / lb[r];
            att[((size_t)(b * 2048 + i)) * DMODEL + h * 64 + d] = (f16)val;
        }
    }
}

// ------------------------------------------------------------- K3: out project
__global__ __launch_bounds__(256, 3) void out_proj(
    const f16* __restrict__ att, const f16* __restrict__ wo16, const float* __restrict__ bo,
    float* __restrict__ out)
{
    __shared__ f16 As[128 * 64];
    __shared__ f16 Bs[128 * 64];

    const int tid = threadIdx.x, lane = tid & 63, w = tid >> 6;
    const int i_l = lane & 15, hi = lane >> 4;
    const int wr = w >> 1, wc = w & 1;

    const int nbid = blockIdx.y * 8 + blockIdx.x;
    const int swz = (nbid & 7) * 32 + (nbid >> 3);
    const int row0 = (swz >> 3) * 128;
    const int col0 = (swz & 7) * 128;

    const int lr = lane >> 3, lc = lane & 7;
    const int sc = (lc ^ lr) << 3;

    f32x4 acc[4][4] = {};

    for (int kk = 0; kk < DMODEL; kk += 64) {
        #pragma unroll
        for (int c = 0; c < 4; ++c) {
            int row = w * 32 + c * 8;
            gload16(&att[(size_t)(row0 + row + lr) * DMODEL + kk + sc], &As[row * 64]);
            gload16(&wo16[(size_t)(col0 + row + lr) * DMODEL + kk + sc], &Bs[row * 64]);
        }
        __syncthreads();

        f16x8 bfr[4][2];
        #pragma unroll
        for (int ni = 0; ni < 4; ++ni)
            #pragma unroll
            for (int ks = 0; ks < 2; ++ks)
                bfr[ni][ks] = *(const f16x8*)&Bs[(wc * 64 + ni * 16 + i_l) * 64 + (((ks * 4 + hi) ^ (i_l & 7)) << 3)];
        __builtin_amdgcn_s_setprio(1);
        #pragma unroll
        for (int mi = 0; mi < 4; ++mi) {
            f16x8 afr[2];
            #pragma unroll
            for (int ks = 0; ks < 2; ++ks)
                afr[ks] = *(const f16x8*)&As[(wr * 64 + mi * 16 + i_l) * 64 + (((ks * 4 + hi) ^ (i_l & 7)) << 3)];
            #pragma unroll
            for (int ni = 0; ni < 4; ++ni)
                #pragma unroll
                for (int ks = 0; ks < 2; ++ks)
                    acc[mi][ni] = __builtin_amdgcn_mfma_f32_16x16x32_f16(afr[ks], bfr[ni][ks], acc[mi][ni], 0, 0, 0);
        }
        __builtin_amdgcn_s_setprio(0);
        __syncthreads();
    }

    #pragma unroll
    for (int mi = 0; mi < 4; ++mi)
        #pragma unroll
        for (int ni = 0; ni < 4; ++ni) {
            int col = col0 + wc * 64 + ni * 16 + i_l;
            float bc = bo[col];
            #pragma unroll
            for (int r = 0; r < 4; ++r) {
                int row = row0 + wr * 64 + mi * 16 + hi * 4 + r;
                out[(size_t)row * DMODEL + col] = acc[mi][ni][r] + bc;
            }
        }
}

// ----------------------------------------------------------------- launch
extern "C" void kernel_launch(void* const* d_in, const int* in_sizes, int n_in,
                              void* d_out, int out_size, void* d_ws, size_t ws_size,
                              hipStream_t stream) {
    const float* q   = (const float*)d_in[0];
    const float* k   = (const float*)d_in[1];
    const float* v   = (const float*)d_in[2];
    const float* rel = (const float*)d_in[3];
    const float* wq  = (const float*)d_in[4];
    const float* bq  = (const float*)d_in[5];
    const float* wk  = (const float*)d_in[6];
    const float* bk  = (const float*)d_in[7];
    const float* wv  = (const float*)d_in[8];
    const float* bv  = (const float*)d_in[9];
    const float* wo  = (const float*)d_in[10];
    const float* bo  = (const float*)d_in[11];
    float* out = (float*)d_out;

    const size_t SX = (size_t)NTOK * DMODEL;      // 4194304 halves
    const size_t SW = (size_t)DMODEL * DMODEL;    // 1048576
    const size_t SR = (size_t)2 * MAXLEN * DKDIM; // 262144

    f16* ws    = (f16*)d_ws;
    f16* x16q  = ws;                  // converted inputs (cvt_all order)
    f16* x16k  = x16q + SX;
    f16* x16v  = x16k + SX;
    f16* wq16  = x16v + SX;
    f16* wk16  = wq16 + SW;
    f16* wv16  = wk16 + SW;
    f16* wo16  = wv16 + SW;
    f16* rel16 = wo16 + SW;
    f16* qh16  = rel16 + SR;
    f16* kh16  = qh16 + SX;
    f16* vt16  = kh16 + SX;
    f16* att16 = x16q;                // alias: x16q dead after qkv_proj

    cvt_all<<<dim3(2048), 256, 0, stream>>>(q, k, v, wq, wk, wv, wo, rel, ws);
    qkv_proj<<<dim3(8, 32, 3), 256, 0, stream>>>(x16q, x16k, x16v, wq16, wk16, wv16,
                                                 bq, bk, bv, qh16, kh16, vt16);
    flash_attn<<<dim3(32, 32), 256, 0, stream>>>(qh16, kh16, vt16, rel16, att16);
    out_proj<<<dim3(8, 32), 256, 0, stream>>>(att16, wo16, bo, out);
}